// Round 7
// baseline (81.879 us; speedup 1.0000x reference)
//
#include <hip/hip_runtime.h>
#include <hip/hip_bf16.h>
#include <math.h>

#define H_N 16
#define DH 64
#define LSEQ 1024
#define BATCH 2
#define NSLOT 2048
#define DMODEL 1024

typedef __bf16 bf16x8 __attribute__((ext_vector_type(8)));
typedef __bf16 bf16x4 __attribute__((ext_vector_type(4)));
typedef float f32x4 __attribute__((ext_vector_type(4)));

// ---------- fused setup: fp32->bf16 of x/Wqkv/Wproj + freq tables, one launch ----------
__global__ __launch_bounds__(256) void k_setup(const float* __restrict__ x,
                                               const float* __restrict__ Wqkv,
                                               const float* __restrict__ Wproj,
                                               const float* __restrict__ topo,
                                               const float* __restrict__ Wfreq,
                                               __bf16* __restrict__ xb,
                                               __bf16* __restrict__ Wqkvb,
                                               __bf16* __restrict__ Wprojb,
                                               float* __restrict__ cosb,
                                               float* __restrict__ sinb) {
    int blk = blockIdx.x;
    if (blk < 6144) {
        const float* in;
        __bf16* out;
        int base;
        if (blk < 2048)      { in = x;     out = xb;     base = blk; }
        else if (blk < 5120) { in = Wqkv;  out = Wqkvb;  base = blk - 2048; }
        else                 { in = Wproj; out = Wprojb; base = blk - 5120; }
        int i = (base * 256 + threadIdx.x) * 4;
        float4 v = *reinterpret_cast<const float4*>(in + i);
        struct B4 { __bf16 a, b, c, d; };
        B4 o{(__bf16)v.x, (__bf16)v.y, (__bf16)v.z, (__bf16)v.w};
        *reinterpret_cast<B4*>(out + i) = o;
    } else {
        int s = (blk - 6144) * 8 + (threadIdx.x >> 5);
        int j = threadIdx.x & 31;
        float f = 0.f;
#pragma unroll
        for (int t = 0; t < 8; ++t) f += topo[s * 8 + t] * Wfreq[j * 8 + t];
        cosb[s * 32 + j] = cosf(f);
        sinb[s * 32 + j] = sinf(f);
    }
}

// ---------- MFMA GEMM core: C[128x128] = A[128xK] * B[128xK]^T ----------
__device__ __forceinline__ void gemm_core(const __bf16* __restrict__ A,
                                          const __bf16* __restrict__ Bm,
                                          int K, int m0, int n0,
                                          __bf16* As, __bf16* Bs,
                                          f32x4 acc[4][4],
                                          int tid, int wr, int wc, int lane) {
    const f32x4 z = {0.f, 0.f, 0.f, 0.f};
#pragma unroll
    for (int m = 0; m < 4; ++m)
#pragma unroll
        for (int n = 0; n < 4; ++n) acc[m][n] = z;

    const int wv = tid >> 6;
    for (int k0 = 0; k0 < K; k0 += 64) {
        __syncthreads();
#pragma unroll
        for (int i = 0; i < 4; ++i) {
            int lin = i * 256 + tid;
            int row = lin >> 3, slot = lin & 7;
            int srcs = slot ^ (row & 7);
            const __bf16* ga = A + (size_t)(m0 + row) * K + k0 + srcs * 8;
            const __bf16* gb = Bm + (size_t)(n0 + row) * K + k0 + srcs * 8;
            __bf16* la = As + i * 2048 + wv * 512;
            __bf16* lb = Bs + i * 2048 + wv * 512;
            __builtin_amdgcn_global_load_lds((const __attribute__((address_space(1))) void*)ga,
                                             (__attribute__((address_space(3))) void*)la, 16, 0, 0);
            __builtin_amdgcn_global_load_lds((const __attribute__((address_space(1))) void*)gb,
                                             (__attribute__((address_space(3))) void*)lb, 16, 0, 0);
        }
        __syncthreads();
        __builtin_amdgcn_s_setprio(1);
#pragma unroll
        for (int kk = 0; kk < 2; ++kk) {
            bf16x8 af[4], bfr[4];
#pragma unroll
            for (int m = 0; m < 4; ++m) {
                int row = wr * 64 + m * 16 + (lane & 15);
                int k16 = kk * 4 + (lane >> 4);
                int slot = k16 ^ (row & 7);
                af[m] = *reinterpret_cast<const bf16x8*>(As + row * 64 + slot * 8);
            }
#pragma unroll
            for (int n = 0; n < 4; ++n) {
                int col = wc * 64 + n * 16 + (lane & 15);
                int k16 = kk * 4 + (lane >> 4);
                int slot = k16 ^ (col & 7);
                bfr[n] = *reinterpret_cast<const bf16x8*>(Bs + col * 64 + slot * 8);
            }
#pragma unroll
            for (int m = 0; m < 4; ++m)
#pragma unroll
                for (int n = 0; n < 4; ++n)
                    acc[m][n] = __builtin_amdgcn_mfma_f32_16x16x32_bf16(af[m], bfr[n], acc[m][n], 0, 0, 0);
        }
        __builtin_amdgcn_s_setprio(0);
    }
}

// ---------- GEMM1 (x @ Wqkv^T) + RoPE epilogue -> bf16 Q,K (h,s,d) and Vt (h,d,s),
// all stores coalesced via LDS repack (stride 144: 16B-aligned, bank-optimal) ----------
__global__ __launch_bounds__(256, 2) void k_qkv_mfma(const __bf16* __restrict__ xb,
                                                     const __bf16* __restrict__ Wb,
                                                     const float* __restrict__ cosb,
                                                     const float* __restrict__ sinb,
                                                     __bf16* __restrict__ Qb,
                                                     __bf16* __restrict__ Kb,
                                                     __bf16* __restrict__ Vtb) {
    __shared__ __bf16 SMEM[128 * 144];  // 36,864 B: As|Bs during GEMM, repack tile L after
    __bf16* As = SMEM;
    __bf16* Bs = SMEM + 8192;
    // XCD-chunked swizzle: 384 blocks, 48/XCD = 3 col-bands x 16 rows
    int lin = blockIdx.x + gridDim.x * blockIdx.y;
    int newlin = (lin & 7) * 48 + (lin >> 3);
    const int m0 = (newlin & 15) * 128, n0 = (newlin >> 4) * 128;
    const int tid = threadIdx.x, lane = tid & 63, w = tid >> 6;
    const int wr = w >> 1, wc = w & 1;
    const int l15 = lane & 15, g = lane >> 4;
    f32x4 acc[4][4];
    gemm_core(xb, Wb, DMODEL, m0, n0, As, Bs, acc, tid, wr, wc, lane);
    __syncthreads();  // all waves done reading As/Bs; SMEM reused as L

    const int part = n0 >> 10;          // 0=q 1=k 2=v (uniform per block)
    const int hbase = (n0 >> 6) & 15;

    if (part < 2) {
        // RoPE + repack row-major L[s_local][c_local]
#pragma unroll
        for (int n = 0; n < 4; ++n) {
            int c_local = wc * 64 + n * 16 + l15;
            int jj = (c_local & 63) >> 1;
#pragma unroll
            for (int m = 0; m < 4; ++m) {
#pragma unroll
                for (int j = 0; j < 4; ++j) {
                    int s_local = wr * 64 + m * 16 + g * 4 + j;
                    int s = m0 + s_local;
                    float v = acc[m][n][j];
                    float partner = __shfl_xor(v, 1);
                    float cs = cosb[s * 32 + jj], sn = sinb[s * 32 + jj];
                    float outv = (c_local & 1) ? fmaf(v, cs, partner * sn)
                                               : fmaf(v, cs, -partner * sn);
                    SMEM[s_local * 144 + c_local] = (__bf16)outv;
                }
            }
        }
        __syncthreads();
        __bf16* dst = (part == 0) ? Qb : Kb;
        const int i = tid & 7;
#pragma unroll
        for (int p = 0; p < 8; ++p) {
            int seg = p * 32 + (tid >> 3);
            int sl = seg >> 1, hh = seg & 1;
            bf16x8 v = *reinterpret_cast<const bf16x8*>(&SMEM[sl * 144 + hh * 64 + i * 8]);
            *reinterpret_cast<bf16x8*>(
                &dst[((size_t)(hbase + hh) * NSLOT + m0 + sl) * DH + i * 8]) = v;
        }
    } else {
        // V: repack transposed L[c_local][s_local]
#pragma unroll
        for (int n = 0; n < 4; ++n) {
            int c_local = wc * 64 + n * 16 + l15;
#pragma unroll
            for (int m = 0; m < 4; ++m) {
#pragma unroll
                for (int j = 0; j < 4; ++j) {
                    int s_local = wr * 64 + m * 16 + g * 4 + j;
                    SMEM[c_local * 144 + s_local] = (__bf16)acc[m][n][j];
                }
            }
        }
        __syncthreads();
        const int i = tid & 7;
#pragma unroll
        for (int p = 0; p < 8; ++p) {
            int seg = p * 32 + (tid >> 3);
            int d2 = seg >> 1, sh = seg & 1;
            bf16x8 v = *reinterpret_cast<const bf16x8*>(&SMEM[d2 * 144 + sh * 64 + i * 8]);
            *reinterpret_cast<bf16x8*>(
                &Vtb[((size_t)(hbase + (d2 >> 6)) * DH + (d2 & 63)) * NSLOT + m0 + sh * 64 + i * 8]) = v;
        }
    }
}

// ---------- MFMA flash attention v6: no online-max, lane-local denominator,
// coalesced AO store via per-wave LDS repack ----------
__global__ __launch_bounds__(256, 2) void k_attn6(const __bf16* __restrict__ Qg,
                                                  const __bf16* __restrict__ Kg,
                                                  const __bf16* __restrict__ Vt,
                                                  __bf16* __restrict__ AO) {
    // 512 blocks = 8 XCDs x 64; each XCD owns 4 whole (b,h) groups
    int lin = blockIdx.x + 16 * (blockIdx.y + 16 * blockIdx.z);
    int newlin = (lin & 7) * 64 + (lin >> 3);
    const int bx = newlin & 15;          // query-64 tile
    const int h = (newlin >> 4) & 15;
    const int b = newlin >> 8;

    const int tid = threadIdx.x, w = tid >> 6, lane = tid & 63;
    const int l15 = lane & 15, g = lane >> 4;
    const int q0 = bx * 64 + w * 16;     // this wave's 16 queries

    __shared__ __bf16 Ks[2][64 * 64];
    __shared__ __bf16 Vs[2][64 * 64];
    __shared__ __bf16 P_lds[4][16 * 72];

    const __bf16* Qh = Qg + ((size_t)h * NSLOT + b * LSEQ) * DH;
    const __bf16* Kh = Kg + ((size_t)h * NSLOT + b * LSEQ) * DH;
    const __bf16* Vh = Vt + ((size_t)h * DH) * NSLOT + b * LSEQ;

    // persistent Q fragments
    bf16x8 qf[2];
#pragma unroll
    for (int g2 = 0; g2 < 2; ++g2)
        qf[g2] = *reinterpret_cast<const bf16x8*>(Qh + (size_t)(q0 + l15) * DH + g2 * 32 + g * 8);

    const f32x4 z = {0.f, 0.f, 0.f, 0.f};
    f32x4 ao[4];
#pragma unroll
    for (int dt = 0; dt < 4; ++dt) ao[dt] = z;
    float lsum[4] = {0.f, 0.f, 0.f, 0.f};

    const int nch = bx + 1;

    // stage chunk 0 into buffer 0 (inverse-swizzled source, rule 21)
#pragma unroll
    for (int i = 0; i < 2; ++i) {
        int u = i * 256 + tid;
        int row = u >> 3, slot = u & 7;
        int srcs = slot ^ (row & 7);
        const __bf16* ga = Kh + (size_t)row * DH + srcs * 8;
        const __bf16* gv = Vh + (size_t)row * NSLOT + srcs * 8;
        __builtin_amdgcn_global_load_lds((const __attribute__((address_space(1))) void*)ga,
                                         (__attribute__((address_space(3))) void*)(&Ks[0][u * 8]), 16, 0, 0);
        __builtin_amdgcn_global_load_lds((const __attribute__((address_space(1))) void*)gv,
                                         (__attribute__((address_space(3))) void*)(&Vs[0][u * 8]), 16, 0, 0);
    }
    __syncthreads();

    for (int ch = 0; ch < nch; ++ch) {
        const int cur = ch & 1;
        if (ch + 1 < nch) {
            const int nsp = (ch + 1) * 64;
#pragma unroll
            for (int i = 0; i < 2; ++i) {
                int u = i * 256 + tid;
                int row = u >> 3, slot = u & 7;
                int srcs = slot ^ (row & 7);
                const __bf16* ga = Kh + (size_t)(nsp + row) * DH + srcs * 8;
                const __bf16* gv = Vh + (size_t)row * NSLOT + nsp + srcs * 8;
                __builtin_amdgcn_global_load_lds((const __attribute__((address_space(1))) void*)ga,
                                                 (__attribute__((address_space(3))) void*)(&Ks[1 - cur][u * 8]), 16, 0, 0);
                __builtin_amdgcn_global_load_lds((const __attribute__((address_space(1))) void*)gv,
                                                 (__attribute__((address_space(3))) void*)(&Vs[1 - cur][u * 8]), 16, 0, 0);
            }
        }

        // ---- QK^T from LDS (swizzled reads) ----
        f32x4 s[4];
#pragma unroll
        for (int n = 0; n < 4; ++n) s[n] = z;
        __builtin_amdgcn_s_setprio(1);
#pragma unroll
        for (int g2 = 0; g2 < 2; ++g2) {
#pragma unroll
            for (int n = 0; n < 4; ++n) {
                int r = n * 16 + l15;
                int slot = ((g2 << 2) + g) ^ (r & 7);
                bf16x8 kf = *reinterpret_cast<const bf16x8*>(&Ks[cur][r * 64 + slot * 8]);
                s[n] = __builtin_amdgcn_mfma_f32_16x16x32_bf16(qf[g2], kf, s[n], 0, 0, 0);
            }
        }
        __builtin_amdgcn_s_setprio(0);

        // ---- p = exp(s*scale), mask -> 0; lane-local denominator ----
        const bool last = (ch == nch - 1);
        const int sp0 = ch * 64;
#pragma unroll
        for (int n = 0; n < 4; ++n) {
            int key = sp0 + n * 16 + l15;
#pragma unroll
            for (int j = 0; j < 4; ++j) {
                float sc = s[n][j] * 0.125f;
                if (last && key > q0 + g * 4 + j) sc = -INFINITY;
                float p = __expf(sc);
                s[n][j] = p;
                lsum[j] += p;
            }
        }

        // ---- P -> LDS (bf16), read back as A-fragments ----
#pragma unroll
        for (int j = 0; j < 4; ++j)
#pragma unroll
            for (int n = 0; n < 4; ++n)
                P_lds[w][(g * 4 + j) * 72 + n * 16 + l15] = (__bf16)s[n][j];

        bf16x8 pf[2];
        pf[0] = *reinterpret_cast<const bf16x8*>(&P_lds[w][l15 * 72 + g * 8]);
        pf[1] = *reinterpret_cast<const bf16x8*>(&P_lds[w][l15 * 72 + 32 + g * 8]);

        // ---- O += P @ V ----
        __builtin_amdgcn_s_setprio(1);
#pragma unroll
        for (int g2 = 0; g2 < 2; ++g2) {
#pragma unroll
            for (int dt = 0; dt < 4; ++dt) {
                int rv = dt * 16 + l15;
                int slot = ((g2 << 2) + g) ^ (rv & 7);
                bf16x8 vf = *reinterpret_cast<const bf16x8*>(&Vs[cur][rv * 64 + slot * 8]);
                ao[dt] = __builtin_amdgcn_mfma_f32_16x16x32_bf16(pf[g2], vf, ao[dt], 0, 0, 0);
            }
        }
        __builtin_amdgcn_s_setprio(0);

        __syncthreads();
    }

    // ---- denominator reduction (16-lane groups) ----
    float lrow[4];
#pragma unroll
    for (int j = 0; j < 4; ++j) {
        float v = lsum[j];
#pragma unroll
        for (int off = 1; off < 16; off <<= 1) v += __shfl_xor(v, off);
        lrow[j] = v;
    }

    // ---- normalize into per-wave LDS tile, then coalesced 128B-segment store ----
#pragma unroll
    for (int dt = 0; dt < 4; ++dt)
#pragma unroll
        for (int j = 0; j < 4; ++j)
            P_lds[w][(g * 4 + j) * 72 + dt * 16 + l15] = (__bf16)(ao[dt][j] / lrow[j]);

    const int ii = lane & 7;
#pragma unroll
    for (int p = 0; p < 2; ++p) {
        int r = p * 8 + (lane >> 3);
        bf16x8 v = *reinterpret_cast<const bf16x8*>(&P_lds[w][r * 72 + ii * 8]);
        *reinterpret_cast<bf16x8*>(
            &AO[(size_t)(b * LSEQ + q0 + r) * DMODEL + h * 64 + ii * 8]) = v;
    }
}

// ---------- proj GEMM (AO @ Wproj^T) -> fp32 out ----------
__global__ __launch_bounds__(256, 2) void k_proj_mfma(const __bf16* __restrict__ AO,
                                                      const __bf16* __restrict__ Wb,
                                                      float* __restrict__ out) {
    __shared__ __bf16 As[128 * 64];
    __shared__ __bf16 Bs[128 * 64];
    // XCD-chunked swizzle: 128 blocks, 16/XCD = 1 col-band x 16 rows
    int lin = blockIdx.x + gridDim.x * blockIdx.y;
    int newlin = (lin & 7) * 16 + (lin >> 3);
    const int m0 = (newlin & 15) * 128, n0 = (newlin >> 4) * 128;
    const int tid = threadIdx.x, lane = tid & 63, w = tid >> 6;
    const int wr = w >> 1, wc = w & 1;
    f32x4 acc[4][4];
    gemm_core(AO, Wb, DMODEL, m0, n0, As, Bs, acc, tid, wr, wc, lane);

#pragma unroll
    for (int n = 0; n < 4; ++n) {
        int c = n0 + wc * 64 + n * 16 + (lane & 15);
#pragma unroll
        for (int m = 0; m < 4; ++m) {
#pragma unroll
            for (int j = 0; j < 4; ++j) {
                int s = m0 + wr * 64 + m * 16 + (lane >> 4) * 4 + j;
                out[(size_t)s * DMODEL + c] = acc[m][n][j];
            }
        }
    }
}

extern "C" void kernel_launch(void* const* d_in, const int* in_sizes, int n_in,
                              void* d_out, int out_size, void* d_ws, size_t ws_size,
                              hipStream_t stream) {
    const float* x     = (const float*)d_in[0];  // (B, L, D)
    const float* topo  = (const float*)d_in[1];  // (B, L, 8)
    const float* Wqkv  = (const float*)d_in[4];  // (3D, D)
    const float* Wproj = (const float*)d_in[5];  // (D, D)
    const float* Wfreq = (const float*)d_in[6];  // (32, 8)
    float* out = (float*)d_out;                  // (B, L, D) fp32

    char* wsb = (char*)d_ws;
    __bf16* xb     = (__bf16*)(wsb + 0);                        // 4 MB
    __bf16* Wqkvb  = (__bf16*)(wsb + (4u << 20));               // 6 MB
    __bf16* Wprojb = (__bf16*)(wsb + (10u << 20));              // 2 MB
    float*  cosb   = (float*)(wsb + (12u << 20));               // 256 KB
    float*  sinb   = (float*)(wsb + (12u << 20) + 262144);      // 256 KB
    __bf16* Qb     = (__bf16*)(wsb + (12u << 20) + 524288);     // 4 MB
    __bf16* Kb     = (__bf16*)(wsb + (16u << 20) + 524288);     // 4 MB
    __bf16* Vtb    = (__bf16*)(wsb + (20u << 20) + 524288);     // 4 MB
    __bf16* AO     = (__bf16*)(wsb + (24u << 20) + 524288);     // 4 MB -> ~28.5 MB

    hipLaunchKernelGGL(k_setup, dim3(6400), dim3(256), 0, stream,
                       x, Wqkv, Wproj, topo, Wfreq, xb, Wqkvb, Wprojb, cosb, sinb);
    hipLaunchKernelGGL(k_qkv_mfma, dim3(3072 / 128, NSLOT / 128), dim3(256), 0, stream,
                       xb, Wqkvb, cosb, sinb, Qb, Kb, Vtb);
    hipLaunchKernelGGL(k_attn6, dim3(LSEQ / 64, H_N, BATCH), dim3(256), 0, stream,
                       Qb, Kb, Vtb, AO);
    hipLaunchKernelGGL(k_proj_mfma, dim3(DMODEL / 128, NSLOT / 128), dim3(256), 0, stream,
                       AO, Wprojb, out);
}

// Round 8
// 74.302 us; speedup vs baseline: 1.1020x; 1.1020x over previous
//
#include <hip/hip_runtime.h>
#include <hip/hip_bf16.h>
#include <math.h>

#define H_N 16
#define DH 64
#define LSEQ 1024
#define BATCH 2
#define NSLOT 2048
#define DMODEL 1024

typedef __bf16 bf16x8 __attribute__((ext_vector_type(8)));
typedef __bf16 bf16x4 __attribute__((ext_vector_type(4)));
typedef float f32x4 __attribute__((ext_vector_type(4)));

// ---------- fused setup: fp32->bf16 of x/Wqkv/Wproj + freq tables, one launch ----------
__global__ __launch_bounds__(256) void k_setup(const float* __restrict__ x,
                                               const float* __restrict__ Wqkv,
                                               const float* __restrict__ Wproj,
                                               const float* __restrict__ topo,
                                               const float* __restrict__ Wfreq,
                                               __bf16* __restrict__ xb,
                                               __bf16* __restrict__ Wqkvb,
                                               __bf16* __restrict__ Wprojb,
                                               float* __restrict__ cosb,
                                               float* __restrict__ sinb) {
    int blk = blockIdx.x;
    if (blk < 6144) {
        const float* in;
        __bf16* out;
        int base;
        if (blk < 2048)      { in = x;     out = xb;     base = blk; }
        else if (blk < 5120) { in = Wqkv;  out = Wqkvb;  base = blk - 2048; }
        else                 { in = Wproj; out = Wprojb; base = blk - 5120; }
        int i = (base * 256 + threadIdx.x) * 4;
        float4 v = *reinterpret_cast<const float4*>(in + i);
        struct B4 { __bf16 a, b, c, d; };
        B4 o{(__bf16)v.x, (__bf16)v.y, (__bf16)v.z, (__bf16)v.w};
        *reinterpret_cast<B4*>(out + i) = o;
    } else {
        int s = (blk - 6144) * 8 + (threadIdx.x >> 5);
        int j = threadIdx.x & 31;
        float f = 0.f;
#pragma unroll
        for (int t = 0; t < 8; ++t) f += topo[s * 8 + t] * Wfreq[j * 8 + t];
        cosb[s * 32 + j] = cosf(f);
        sinb[s * 32 + j] = sinf(f);
    }
}

// ---------- MFMA GEMM core: C[128x128] = A[128xK] * B[128xK]^T ----------
__device__ __forceinline__ void gemm_core(const __bf16* __restrict__ A,
                                          const __bf16* __restrict__ Bm,
                                          int K, int m0, int n0,
                                          __bf16* As, __bf16* Bs,
                                          f32x4 acc[4][4],
                                          int tid, int wr, int wc, int lane) {
    const f32x4 z = {0.f, 0.f, 0.f, 0.f};
#pragma unroll
    for (int m = 0; m < 4; ++m)
#pragma unroll
        for (int n = 0; n < 4; ++n) acc[m][n] = z;

    const int wv = tid >> 6;
    for (int k0 = 0; k0 < K; k0 += 64) {
        __syncthreads();
#pragma unroll
        for (int i = 0; i < 4; ++i) {
            int lin = i * 256 + tid;
            int row = lin >> 3, slot = lin & 7;
            int srcs = slot ^ (row & 7);
            const __bf16* ga = A + (size_t)(m0 + row) * K + k0 + srcs * 8;
            const __bf16* gb = Bm + (size_t)(n0 + row) * K + k0 + srcs * 8;
            __bf16* la = As + i * 2048 + wv * 512;
            __bf16* lb = Bs + i * 2048 + wv * 512;
            __builtin_amdgcn_global_load_lds((const __attribute__((address_space(1))) void*)ga,
                                             (__attribute__((address_space(3))) void*)la, 16, 0, 0);
            __builtin_amdgcn_global_load_lds((const __attribute__((address_space(1))) void*)gb,
                                             (__attribute__((address_space(3))) void*)lb, 16, 0, 0);
        }
        __syncthreads();
        __builtin_amdgcn_s_setprio(1);
#pragma unroll
        for (int kk = 0; kk < 2; ++kk) {
            bf16x8 af[4], bfr[4];
#pragma unroll
            for (int m = 0; m < 4; ++m) {
                int row = wr * 64 + m * 16 + (lane & 15);
                int k16 = kk * 4 + (lane >> 4);
                int slot = k16 ^ (row & 7);
                af[m] = *reinterpret_cast<const bf16x8*>(As + row * 64 + slot * 8);
            }
#pragma unroll
            for (int n = 0; n < 4; ++n) {
                int col = wc * 64 + n * 16 + (lane & 15);
                int k16 = kk * 4 + (lane >> 4);
                int slot = k16 ^ (col & 7);
                bfr[n] = *reinterpret_cast<const bf16x8*>(Bs + col * 64 + slot * 8);
            }
#pragma unroll
            for (int m = 0; m < 4; ++m)
#pragma unroll
                for (int n = 0; n < 4; ++n)
                    acc[m][n] = __builtin_amdgcn_mfma_f32_16x16x32_bf16(af[m], bfr[n], acc[m][n], 0, 0, 0);
        }
        __builtin_amdgcn_s_setprio(0);
    }
}

// ---------- GEMM1 (x @ Wqkv^T) + RoPE epilogue -> bf16 Q,K (h,s,d) and Vt (h,d,s) ----------
__global__ __launch_bounds__(256, 2) void k_qkv_mfma(const __bf16* __restrict__ xb,
                                                     const __bf16* __restrict__ Wb,
                                                     const float* __restrict__ cosb,
                                                     const float* __restrict__ sinb,
                                                     __bf16* __restrict__ Qb,
                                                     __bf16* __restrict__ Kb,
                                                     __bf16* __restrict__ Vtb) {
    __shared__ __bf16 As[128 * 64];
    __shared__ __bf16 Bs[128 * 64];
    // XCD-chunked swizzle: 384 blocks, 48/XCD = 3 col-bands x 16 rows
    int lin = blockIdx.x + gridDim.x * blockIdx.y;
    int newlin = (lin & 7) * 48 + (lin >> 3);
    const int m0 = (newlin & 15) * 128, n0 = (newlin >> 4) * 128;
    const int tid = threadIdx.x, lane = tid & 63, w = tid >> 6;
    const int wr = w >> 1, wc = w & 1;
    f32x4 acc[4][4];
    gemm_core(xb, Wb, DMODEL, m0, n0, As, Bs, acc, tid, wr, wc, lane);

    const int rbase = m0 + wr * 64;
#pragma unroll
    for (int n = 0; n < 4; ++n) {
        int c = n0 + wc * 64 + n * 16 + (lane & 15);
        int part = c >> 10, h = (c >> 6) & 15, d = c & 63, jj = d >> 1;
#pragma unroll
        for (int m = 0; m < 4; ++m) {
            int sbase = rbase + m * 16 + (lane >> 4) * 4;
            if (part < 2) {
                __bf16* dst = (part == 0) ? Qb : Kb;
#pragma unroll
                for (int j = 0; j < 4; ++j) {
                    int s = sbase + j;
                    float v = acc[m][n][j];
                    float partner = __shfl_xor(v, 1);
                    float cs = cosb[s * 32 + jj], sn = sinb[s * 32 + jj];
                    float outv = (d & 1) ? fmaf(v, cs, partner * sn) : fmaf(v, cs, -partner * sn);
                    dst[((size_t)h * NSLOT + s) * DH + d] = (__bf16)outv;
                }
            } else {
                bf16x4 pk;
#pragma unroll
                for (int j = 0; j < 4; ++j) pk[j] = (__bf16)acc[m][n][j];
                *reinterpret_cast<bf16x4*>(&Vtb[((size_t)h * DH + d) * NSLOT + sbase]) = pk;
            }
        }
    }
}

// ---------- MFMA flash attention v8: no online-max, lane-local denominator,
// causal-balanced block mapping: co-resident blocks (t, t+32) have bx summing
// to 15 -> every CU gets exactly 17 chunk-units; both share (b,h) for L2 reuse ----------
__global__ __launch_bounds__(256, 2) void k_attn8(const __bf16* __restrict__ Qg,
                                                  const __bf16* __restrict__ Kg,
                                                  const __bf16* __restrict__ Vt,
                                                  __bf16* __restrict__ AO) {
    int lin = blockIdx.x + 16 * (blockIdx.y + 16 * blockIdx.z);
    const int x = lin & 7;        // XCD (assumed round-robin dispatch)
    const int t = lin >> 3;       // position within XCD, 0..63
    const int b = x >> 2;
    const int h = (x & 3) * 4 + (t & 3);
    const int v = t >> 2;         // 0..15
    const int bx = (v < 8) ? v : 23 - v;   // balanced pairing: bx(v)+bx(v+8)=15

    const int tid = threadIdx.x, w = tid >> 6, lane = tid & 63;
    const int l15 = lane & 15, g = lane >> 4;
    const int q0 = bx * 64 + w * 16;     // this wave's 16 queries

    __shared__ __bf16 Ks[2][64 * 64];
    __shared__ __bf16 Vs[2][64 * 64];
    __shared__ __bf16 P_lds[4][16 * 72];

    const __bf16* Qh = Qg + ((size_t)h * NSLOT + b * LSEQ) * DH;
    const __bf16* Kh = Kg + ((size_t)h * NSLOT + b * LSEQ) * DH;
    const __bf16* Vh = Vt + ((size_t)h * DH) * NSLOT + b * LSEQ;

    // persistent Q fragments
    bf16x8 qf[2];
#pragma unroll
    for (int g2 = 0; g2 < 2; ++g2)
        qf[g2] = *reinterpret_cast<const bf16x8*>(Qh + (size_t)(q0 + l15) * DH + g2 * 32 + g * 8);

    const f32x4 z = {0.f, 0.f, 0.f, 0.f};
    f32x4 ao[4];
#pragma unroll
    for (int dt = 0; dt < 4; ++dt) ao[dt] = z;
    float lsum[4] = {0.f, 0.f, 0.f, 0.f};

    const int nch = bx + 1;

    // stage chunk 0 into buffer 0 (inverse-swizzled source, rule 21)
#pragma unroll
    for (int i = 0; i < 2; ++i) {
        int u = i * 256 + tid;
        int row = u >> 3, slot = u & 7;
        int srcs = slot ^ (row & 7);
        const __bf16* ga = Kh + (size_t)row * DH + srcs * 8;
        const __bf16* gv = Vh + (size_t)row * NSLOT + srcs * 8;
        __builtin_amdgcn_global_load_lds((const __attribute__((address_space(1))) void*)ga,
                                         (__attribute__((address_space(3))) void*)(&Ks[0][u * 8]), 16, 0, 0);
        __builtin_amdgcn_global_load_lds((const __attribute__((address_space(1))) void*)gv,
                                         (__attribute__((address_space(3))) void*)(&Vs[0][u * 8]), 16, 0, 0);
    }
    __syncthreads();

    for (int ch = 0; ch < nch; ++ch) {
        const int cur = ch & 1;
        if (ch + 1 < nch) {
            const int nsp = (ch + 1) * 64;
#pragma unroll
            for (int i = 0; i < 2; ++i) {
                int u = i * 256 + tid;
                int row = u >> 3, slot = u & 7;
                int srcs = slot ^ (row & 7);
                const __bf16* ga = Kh + (size_t)(nsp + row) * DH + srcs * 8;
                const __bf16* gv = Vh + (size_t)row * NSLOT + nsp + srcs * 8;
                __builtin_amdgcn_global_load_lds((const __attribute__((address_space(1))) void*)ga,
                                                 (__attribute__((address_space(3))) void*)(&Ks[1 - cur][u * 8]), 16, 0, 0);
                __builtin_amdgcn_global_load_lds((const __attribute__((address_space(1))) void*)gv,
                                                 (__attribute__((address_space(3))) void*)(&Vs[1 - cur][u * 8]), 16, 0, 0);
            }
        }

        // ---- QK^T from LDS (swizzled reads) ----
        f32x4 s[4];
#pragma unroll
        for (int n = 0; n < 4; ++n) s[n] = z;
        __builtin_amdgcn_s_setprio(1);
#pragma unroll
        for (int g2 = 0; g2 < 2; ++g2) {
#pragma unroll
            for (int n = 0; n < 4; ++n) {
                int r = n * 16 + l15;
                int slot = ((g2 << 2) + g) ^ (r & 7);
                bf16x8 kf = *reinterpret_cast<const bf16x8*>(&Ks[cur][r * 64 + slot * 8]);
                s[n] = __builtin_amdgcn_mfma_f32_16x16x32_bf16(qf[g2], kf, s[n], 0, 0, 0);
            }
        }
        __builtin_amdgcn_s_setprio(0);

        // ---- p = exp(s*scale), mask -> 0; lane-local denominator ----
        const bool last = (ch == nch - 1);
        const int sp0 = ch * 64;
#pragma unroll
        for (int n = 0; n < 4; ++n) {
            int key = sp0 + n * 16 + l15;
#pragma unroll
            for (int j = 0; j < 4; ++j) {
                float sc = s[n][j] * 0.125f;
                if (last && key > q0 + g * 4 + j) sc = -INFINITY;
                float p = __expf(sc);
                s[n][j] = p;
                lsum[j] += p;
            }
        }

        // ---- P -> LDS (bf16), read back as A-fragments ----
#pragma unroll
        for (int j = 0; j < 4; ++j)
#pragma unroll
            for (int n = 0; n < 4; ++n)
                P_lds[w][(g * 4 + j) * 72 + n * 16 + l15] = (__bf16)s[n][j];

        bf16x8 pf[2];
        pf[0] = *reinterpret_cast<const bf16x8*>(&P_lds[w][l15 * 72 + g * 8]);
        pf[1] = *reinterpret_cast<const bf16x8*>(&P_lds[w][l15 * 72 + 32 + g * 8]);

        // ---- O += P @ V ----
        __builtin_amdgcn_s_setprio(1);
#pragma unroll
        for (int g2 = 0; g2 < 2; ++g2) {
#pragma unroll
            for (int dt = 0; dt < 4; ++dt) {
                int rv = dt * 16 + l15;
                int slot = ((g2 << 2) + g) ^ (rv & 7);
                bf16x8 vf = *reinterpret_cast<const bf16x8*>(&Vs[cur][rv * 64 + slot * 8]);
                ao[dt] = __builtin_amdgcn_mfma_f32_16x16x32_bf16(pf[g2], vf, ao[dt], 0, 0, 0);
            }
        }
        __builtin_amdgcn_s_setprio(0);

        __syncthreads();
    }

    // ---- denominator reduction (16-lane groups) ----
    float lrow[4];
#pragma unroll
    for (int j = 0; j < 4; ++j) {
        float vv = lsum[j];
#pragma unroll
        for (int off = 1; off < 16; off <<= 1) vv += __shfl_xor(vv, off);
        lrow[j] = vv;
    }

#pragma unroll
    for (int dt = 0; dt < 4; ++dt)
#pragma unroll
        for (int j = 0; j < 4; ++j) {
            int q = q0 + g * 4 + j;
            AO[(size_t)(b * LSEQ + q) * DMODEL + h * 64 + dt * 16 + l15] =
                (__bf16)(ao[dt][j] / lrow[j]);
        }
}

// ---------- proj GEMM (AO @ Wproj^T) -> fp32 out ----------
__global__ __launch_bounds__(256, 2) void k_proj_mfma(const __bf16* __restrict__ AO,
                                                      const __bf16* __restrict__ Wb,
                                                      float* __restrict__ out) {
    __shared__ __bf16 As[128 * 64];
    __shared__ __bf16 Bs[128 * 64];
    // XCD-chunked swizzle: 128 blocks, 16/XCD = 1 col-band x 16 rows
    int lin = blockIdx.x + gridDim.x * blockIdx.y;
    int newlin = (lin & 7) * 16 + (lin >> 3);
    const int m0 = (newlin & 15) * 128, n0 = (newlin >> 4) * 128;
    const int tid = threadIdx.x, lane = tid & 63, w = tid >> 6;
    const int wr = w >> 1, wc = w & 1;
    f32x4 acc[4][4];
    gemm_core(AO, Wb, DMODEL, m0, n0, As, Bs, acc, tid, wr, wc, lane);

#pragma unroll
    for (int n = 0; n < 4; ++n) {
        int c = n0 + wc * 64 + n * 16 + (lane & 15);
#pragma unroll
        for (int m = 0; m < 4; ++m) {
#pragma unroll
            for (int j = 0; j < 4; ++j) {
                int s = m0 + wr * 64 + m * 16 + (lane >> 4) * 4 + j;
                out[(size_t)s * DMODEL + c] = acc[m][n][j];
            }
        }
    }
}

extern "C" void kernel_launch(void* const* d_in, const int* in_sizes, int n_in,
                              void* d_out, int out_size, void* d_ws, size_t ws_size,
                              hipStream_t stream) {
    const float* x     = (const float*)d_in[0];  // (B, L, D)
    const float* topo  = (const float*)d_in[1];  // (B, L, 8)
    const float* Wqkv  = (const float*)d_in[4];  // (3D, D)
    const float* Wproj = (const float*)d_in[5];  // (D, D)
    const float* Wfreq = (const float*)d_in[6];  // (32, 8)
    float* out = (float*)d_out;                  // (B, L, D) fp32

    char* wsb = (char*)d_ws;
    __bf16* xb     = (__bf16*)(wsb + 0);                        // 4 MB
    __bf16* Wqkvb  = (__bf16*)(wsb + (4u << 20));               // 6 MB
    __bf16* Wprojb = (__bf16*)(wsb + (10u << 20));              // 2 MB
    float*  cosb   = (float*)(wsb + (12u << 20));               // 256 KB
    float*  sinb   = (float*)(wsb + (12u << 20) + 262144);      // 256 KB
    __bf16* Qb     = (__bf16*)(wsb + (12u << 20) + 524288);     // 4 MB
    __bf16* Kb     = (__bf16*)(wsb + (16u << 20) + 524288);     // 4 MB
    __bf16* Vtb    = (__bf16*)(wsb + (20u << 20) + 524288);     // 4 MB
    __bf16* AO     = (__bf16*)(wsb + (24u << 20) + 524288);     // 4 MB -> ~28.5 MB

    hipLaunchKernelGGL(k_setup, dim3(6400), dim3(256), 0, stream,
                       x, Wqkv, Wproj, topo, Wfreq, xb, Wqkvb, Wprojb, cosb, sinb);
    hipLaunchKernelGGL(k_qkv_mfma, dim3(3072 / 128, NSLOT / 128), dim3(256), 0, stream,
                       xb, Wqkvb, cosb, sinb, Qb, Kb, Vtb);
    hipLaunchKernelGGL(k_attn8, dim3(LSEQ / 64, H_N, BATCH), dim3(256), 0, stream,
                       Qb, Kb, Vtb, AO);
    hipLaunchKernelGGL(k_proj_mfma, dim3(DMODEL / 128, NSLOT / 128), dim3(256), 0, stream,
                       AO, Wprojb, out);
}

// Round 9
// 65.386 us; speedup vs baseline: 1.2522x; 1.1364x over previous
//
#include <hip/hip_runtime.h>
#include <hip/hip_bf16.h>
#include <math.h>

#define H_N 16
#define DH 64
#define LSEQ 1024
#define BATCH 2
#define NSLOT 2048
#define DMODEL 1024

typedef __bf16 bf16x8 __attribute__((ext_vector_type(8)));
typedef __bf16 bf16x4 __attribute__((ext_vector_type(4)));
typedef float f32x4 __attribute__((ext_vector_type(4)));

// ---------- fused setup: fp32->bf16 of x/Wqkv/Wproj + freq tables, one launch ----------
__global__ __launch_bounds__(256) void k_setup(const float* __restrict__ x,
                                               const float* __restrict__ Wqkv,
                                               const float* __restrict__ Wproj,
                                               const float* __restrict__ topo,
                                               const float* __restrict__ Wfreq,
                                               __bf16* __restrict__ xb,
                                               __bf16* __restrict__ Wqkvb,
                                               __bf16* __restrict__ Wprojb,
                                               float* __restrict__ cosb,
                                               float* __restrict__ sinb) {
    int blk = blockIdx.x;
    if (blk < 6144) {
        const float* in;
        __bf16* out;
        int base;
        if (blk < 2048)      { in = x;     out = xb;     base = blk; }
        else if (blk < 5120) { in = Wqkv;  out = Wqkvb;  base = blk - 2048; }
        else                 { in = Wproj; out = Wprojb; base = blk - 5120; }
        int i = (base * 256 + threadIdx.x) * 4;
        float4 v = *reinterpret_cast<const float4*>(in + i);
        struct B4 { __bf16 a, b, c, d; };
        B4 o{(__bf16)v.x, (__bf16)v.y, (__bf16)v.z, (__bf16)v.w};
        *reinterpret_cast<B4*>(out + i) = o;
    } else {
        int s = (blk - 6144) * 8 + (threadIdx.x >> 5);
        int j = threadIdx.x & 31;
        float f = 0.f;
#pragma unroll
        for (int t = 0; t < 8; ++t) f += topo[s * 8 + t] * Wfreq[j * 8 + t];
        cosb[s * 32 + j] = cosf(f);
        sinb[s * 32 + j] = sinf(f);
    }
}

// ---------- templated MFMA GEMM core: C[BM x BN] = A[BM x K] * B[BN x K]^T ----------
// BK=64, global_load_lds width 16, XOR(row&7) slot swizzle both sides.
// Wave layout 2x2: wave sub-tile (BM/2) x (BN/2). K-loop order identical across tilings.
template <int BM, int BN>
__device__ __forceinline__ void gemm_coreT(const __bf16* __restrict__ A,
                                           const __bf16* __restrict__ Bm,
                                           int K, int m0, int n0,
                                           __bf16* As, __bf16* Bs,
                                           f32x4 acc[BM / 32][BN / 32],
                                           int tid, int wr, int wc, int lane) {
    constexpr int MF = BM / 32, NF = BN / 32;
    const f32x4 z = {0.f, 0.f, 0.f, 0.f};
#pragma unroll
    for (int m = 0; m < MF; ++m)
#pragma unroll
        for (int n = 0; n < NF; ++n) acc[m][n] = z;

    const int l15 = lane & 15, g = lane >> 4;
    const int wv = tid >> 6;
    for (int k0 = 0; k0 < K; k0 += 64) {
        __syncthreads();
#pragma unroll
        for (int i = 0; i < BM / 32; ++i) {
            int u = i * 256 + tid;
            int row = u >> 3, slot = u & 7, srcs = slot ^ (row & 7);
            __builtin_amdgcn_global_load_lds(
                (const __attribute__((address_space(1))) void*)(A + (size_t)(m0 + row) * K + k0 + srcs * 8),
                (__attribute__((address_space(3))) void*)(As + i * 2048 + wv * 512), 16, 0, 0);
        }
#pragma unroll
        for (int i = 0; i < BN / 32; ++i) {
            int u = i * 256 + tid;
            int row = u >> 3, slot = u & 7, srcs = slot ^ (row & 7);
            __builtin_amdgcn_global_load_lds(
                (const __attribute__((address_space(1))) void*)(Bm + (size_t)(n0 + row) * K + k0 + srcs * 8),
                (__attribute__((address_space(3))) void*)(Bs + i * 2048 + wv * 512), 16, 0, 0);
        }
        __syncthreads();
        __builtin_amdgcn_s_setprio(1);
#pragma unroll
        for (int kk = 0; kk < 2; ++kk) {
            const int k16 = kk * 4 + g;
            bf16x8 af[MF], bfr[NF];
#pragma unroll
            for (int m = 0; m < MF; ++m) {
                int row = wr * (BM / 2) + m * 16 + l15;
                int slot = k16 ^ (row & 7);
                af[m] = *reinterpret_cast<const bf16x8*>(As + row * 64 + slot * 8);
            }
#pragma unroll
            for (int n = 0; n < NF; ++n) {
                int col = wc * (BN / 2) + n * 16 + l15;
                int slot = k16 ^ (col & 7);
                bfr[n] = *reinterpret_cast<const bf16x8*>(Bs + col * 64 + slot * 8);
            }
#pragma unroll
            for (int m = 0; m < MF; ++m)
#pragma unroll
                for (int n = 0; n < NF; ++n)
                    acc[m][n] = __builtin_amdgcn_mfma_f32_16x16x32_bf16(af[m], bfr[n], acc[m][n], 0, 0, 0);
        }
        __builtin_amdgcn_s_setprio(0);
    }
}

// ---------- GEMM1 (x @ Wqkv^T) + RoPE epilogue -> bf16 Q,K (h,s,d) and Vt (h,d,s)
// 128x96 tiles -> 512 blocks = 2/CU exact. Part boundaries handled per-column. ----------
__global__ __launch_bounds__(256, 2) void k_qkv_mfma(const __bf16* __restrict__ xb,
                                                     const __bf16* __restrict__ Wb,
                                                     const float* __restrict__ cosb,
                                                     const float* __restrict__ sinb,
                                                     __bf16* __restrict__ Qb,
                                                     __bf16* __restrict__ Kb,
                                                     __bf16* __restrict__ Vtb) {
    __shared__ __bf16 As[128 * 64];
    __shared__ __bf16 Bs[96 * 64];
    // XCD-chunked swizzle: 512 blocks, 64/XCD = 4 col-bands(96) x 16 row-bands
    int lin = blockIdx.x;
    int newlin = (lin & 7) * 64 + (lin >> 3);
    const int m0 = (newlin & 15) * 128, n0 = (newlin >> 4) * 96;
    const int tid = threadIdx.x, lane = tid & 63, w = tid >> 6;
    const int wr = w >> 1, wc = w & 1;
    const int l15 = lane & 15, g = lane >> 4;
    f32x4 acc[4][3];
    gemm_coreT<128, 96>(xb, Wb, DMODEL, m0, n0, As, Bs, acc, tid, wr, wc, lane);

    const int rbase = m0 + wr * 64;
#pragma unroll
    for (int n = 0; n < 3; ++n) {
        int c = n0 + wc * 48 + n * 16 + l15;
        int part = c >> 10, h = (c >> 6) & 15, d = c & 63, jj = d >> 1;
#pragma unroll
        for (int m = 0; m < 4; ++m) {
            int sbase = rbase + m * 16 + g * 4;
            if (part < 2) {
                __bf16* dst = (part == 0) ? Qb : Kb;
#pragma unroll
                for (int j = 0; j < 4; ++j) {
                    int s = sbase + j;
                    float v = acc[m][n][j];
                    float partner = __shfl_xor(v, 1);
                    float cs = cosb[s * 32 + jj], sn = sinb[s * 32 + jj];
                    float outv = (d & 1) ? fmaf(v, cs, partner * sn) : fmaf(v, cs, -partner * sn);
                    dst[((size_t)h * NSLOT + s) * DH + d] = (__bf16)outv;
                }
            } else {
                bf16x4 pk;
#pragma unroll
                for (int j = 0; j < 4; ++j) pk[j] = (__bf16)acc[m][n][j];
                *reinterpret_cast<bf16x4*>(&Vtb[((size_t)h * DH + d) * NSLOT + sbase]) = pk;
            }
        }
    }
}

// ---------- MFMA flash attention v8: no online-max, lane-local denominator,
// causal-balanced block mapping (every CU gets exactly 17 chunk-units) ----------
__global__ __launch_bounds__(256, 2) void k_attn8(const __bf16* __restrict__ Qg,
                                                  const __bf16* __restrict__ Kg,
                                                  const __bf16* __restrict__ Vt,
                                                  __bf16* __restrict__ AO) {
    int lin = blockIdx.x + 16 * (blockIdx.y + 16 * blockIdx.z);
    const int x = lin & 7;        // XCD (round-robin dispatch)
    const int t = lin >> 3;       // position within XCD, 0..63
    const int b = x >> 2;
    const int h = (x & 3) * 4 + (t & 3);
    const int v = t >> 2;         // 0..15
    const int bx = (v < 8) ? v : 23 - v;   // balanced pairing: bx(v)+bx(v+8)=15

    const int tid = threadIdx.x, w = tid >> 6, lane = tid & 63;
    const int l15 = lane & 15, g = lane >> 4;
    const int q0 = bx * 64 + w * 16;

    __shared__ __bf16 Ks[2][64 * 64];
    __shared__ __bf16 Vs[2][64 * 64];
    __shared__ __bf16 P_lds[4][16 * 72];

    const __bf16* Qh = Qg + ((size_t)h * NSLOT + b * LSEQ) * DH;
    const __bf16* Kh = Kg + ((size_t)h * NSLOT + b * LSEQ) * DH;
    const __bf16* Vh = Vt + ((size_t)h * DH) * NSLOT + b * LSEQ;

    bf16x8 qf[2];
#pragma unroll
    for (int g2 = 0; g2 < 2; ++g2)
        qf[g2] = *reinterpret_cast<const bf16x8*>(Qh + (size_t)(q0 + l15) * DH + g2 * 32 + g * 8);

    const f32x4 z = {0.f, 0.f, 0.f, 0.f};
    f32x4 ao[4];
#pragma unroll
    for (int dt = 0; dt < 4; ++dt) ao[dt] = z;
    float lsum[4] = {0.f, 0.f, 0.f, 0.f};

    const int nch = bx + 1;

#pragma unroll
    for (int i = 0; i < 2; ++i) {
        int u = i * 256 + tid;
        int row = u >> 3, slot = u & 7;
        int srcs = slot ^ (row & 7);
        const __bf16* ga = Kh + (size_t)row * DH + srcs * 8;
        const __bf16* gv = Vh + (size_t)row * NSLOT + srcs * 8;
        __builtin_amdgcn_global_load_lds((const __attribute__((address_space(1))) void*)ga,
                                         (__attribute__((address_space(3))) void*)(&Ks[0][u * 8]), 16, 0, 0);
        __builtin_amdgcn_global_load_lds((const __attribute__((address_space(1))) void*)gv,
                                         (__attribute__((address_space(3))) void*)(&Vs[0][u * 8]), 16, 0, 0);
    }
    __syncthreads();

    for (int ch = 0; ch < nch; ++ch) {
        const int cur = ch & 1;
        if (ch + 1 < nch) {
            const int nsp = (ch + 1) * 64;
#pragma unroll
            for (int i = 0; i < 2; ++i) {
                int u = i * 256 + tid;
                int row = u >> 3, slot = u & 7;
                int srcs = slot ^ (row & 7);
                const __bf16* ga = Kh + (size_t)(nsp + row) * DH + srcs * 8;
                const __bf16* gv = Vh + (size_t)row * NSLOT + nsp + srcs * 8;
                __builtin_amdgcn_global_load_lds((const __attribute__((address_space(1))) void*)ga,
                                                 (__attribute__((address_space(3))) void*)(&Ks[1 - cur][u * 8]), 16, 0, 0);
                __builtin_amdgcn_global_load_lds((const __attribute__((address_space(1))) void*)gv,
                                                 (__attribute__((address_space(3))) void*)(&Vs[1 - cur][u * 8]), 16, 0, 0);
            }
        }

        // ---- QK^T from LDS (swizzled reads) ----
        f32x4 s[4];
#pragma unroll
        for (int n = 0; n < 4; ++n) s[n] = z;
        __builtin_amdgcn_s_setprio(1);
#pragma unroll
        for (int g2 = 0; g2 < 2; ++g2) {
#pragma unroll
            for (int n = 0; n < 4; ++n) {
                int r = n * 16 + l15;
                int slot = ((g2 << 2) + g) ^ (r & 7);
                bf16x8 kf = *reinterpret_cast<const bf16x8*>(&Ks[cur][r * 64 + slot * 8]);
                s[n] = __builtin_amdgcn_mfma_f32_16x16x32_bf16(qf[g2], kf, s[n], 0, 0, 0);
            }
        }
        __builtin_amdgcn_s_setprio(0);

        // ---- p = exp(s*scale), mask -> 0; lane-local denominator ----
        const bool last = (ch == nch - 1);
        const int sp0 = ch * 64;
#pragma unroll
        for (int n = 0; n < 4; ++n) {
            int key = sp0 + n * 16 + l15;
#pragma unroll
            for (int j = 0; j < 4; ++j) {
                float sc = s[n][j] * 0.125f;
                if (last && key > q0 + g * 4 + j) sc = -INFINITY;
                float p = __expf(sc);
                s[n][j] = p;
                lsum[j] += p;
            }
        }

        // ---- P -> LDS (bf16), read back as A-fragments ----
#pragma unroll
        for (int j = 0; j < 4; ++j)
#pragma unroll
            for (int n = 0; n < 4; ++n)
                P_lds[w][(g * 4 + j) * 72 + n * 16 + l15] = (__bf16)s[n][j];

        bf16x8 pf[2];
        pf[0] = *reinterpret_cast<const bf16x8*>(&P_lds[w][l15 * 72 + g * 8]);
        pf[1] = *reinterpret_cast<const bf16x8*>(&P_lds[w][l15 * 72 + 32 + g * 8]);

        // ---- O += P @ V ----
        __builtin_amdgcn_s_setprio(1);
#pragma unroll
        for (int g2 = 0; g2 < 2; ++g2) {
#pragma unroll
            for (int dt = 0; dt < 4; ++dt) {
                int rv = dt * 16 + l15;
                int slot = ((g2 << 2) + g) ^ (rv & 7);
                bf16x8 vf = *reinterpret_cast<const bf16x8*>(&Vs[cur][rv * 64 + slot * 8]);
                ao[dt] = __builtin_amdgcn_mfma_f32_16x16x32_bf16(pf[g2], vf, ao[dt], 0, 0, 0);
            }
        }
        __builtin_amdgcn_s_setprio(0);

        __syncthreads();
    }

    // ---- denominator reduction (16-lane groups) ----
    float lrow[4];
#pragma unroll
    for (int j = 0; j < 4; ++j) {
        float vv = lsum[j];
#pragma unroll
        for (int off = 1; off < 16; off <<= 1) vv += __shfl_xor(vv, off);
        lrow[j] = vv;
    }

#pragma unroll
    for (int dt = 0; dt < 4; ++dt)
#pragma unroll
        for (int j = 0; j < 4; ++j) {
            int q = q0 + g * 4 + j;
            AO[(size_t)(b * LSEQ + q) * DMODEL + h * 64 + dt * 16 + l15] =
                (__bf16)(ao[dt][j] / lrow[j]);
        }
}

// ---------- proj GEMM (AO @ Wproj^T) -> fp32 out; 64x64 tiles -> 512 blocks = 2/CU ----------
__global__ __launch_bounds__(256, 2) void k_proj_mfma(const __bf16* __restrict__ AO,
                                                      const __bf16* __restrict__ Wb,
                                                      float* __restrict__ out) {
    __shared__ __bf16 As[64 * 64];
    __shared__ __bf16 Bs[64 * 64];
    // XCD-chunked swizzle: 512 blocks, 64/XCD = 2 col-bands(64) x 32 row-bands
    int lin = blockIdx.x;
    int newlin = (lin & 7) * 64 + (lin >> 3);
    const int m0 = (newlin & 31) * 64, n0 = (newlin >> 5) * 64;
    const int tid = threadIdx.x, lane = tid & 63, w = tid >> 6;
    const int wr = w >> 1, wc = w & 1;
    const int l15 = lane & 15, g = lane >> 4;
    f32x4 acc[2][2];
    gemm_coreT<64, 64>(AO, Wb, DMODEL, m0, n0, As, Bs, acc, tid, wr, wc, lane);

#pragma unroll
    for (int n = 0; n < 2; ++n) {
        int c = n0 + wc * 32 + n * 16 + l15;
#pragma unroll
        for (int m = 0; m < 2; ++m) {
#pragma unroll
            for (int j = 0; j < 4; ++j) {
                int s = m0 + wr * 32 + m * 16 + g * 4 + j;
                out[(size_t)s * DMODEL + c] = acc[m][n][j];
            }
        }
    }
}

extern "C" void kernel_launch(void* const* d_in, const int* in_sizes, int n_in,
                              void* d_out, int out_size, void* d_ws, size_t ws_size,
                              hipStream_t stream) {
    const float* x     = (const float*)d_in[0];  // (B, L, D)
    const float* topo  = (const float*)d_in[1];  // (B, L, 8)
    const float* Wqkv  = (const float*)d_in[4];  // (3D, D)
    const float* Wproj = (const float*)d_in[5];  // (D, D)
    const float* Wfreq = (const float*)d_in[6];  // (32, 8)
    float* out = (float*)d_out;                  // (B, L, D) fp32

    char* wsb = (char*)d_ws;
    __bf16* xb     = (__bf16*)(wsb + 0);                        // 4 MB
    __bf16* Wqkvb  = (__bf16*)(wsb + (4u << 20));               // 6 MB
    __bf16* Wprojb = (__bf16*)(wsb + (10u << 20));              // 2 MB
    float*  cosb   = (float*)(wsb + (12u << 20));               // 256 KB
    float*  sinb   = (float*)(wsb + (12u << 20) + 262144);      // 256 KB
    __bf16* Qb     = (__bf16*)(wsb + (12u << 20) + 524288);     // 4 MB
    __bf16* Kb     = (__bf16*)(wsb + (16u << 20) + 524288);     // 4 MB
    __bf16* Vtb    = (__bf16*)(wsb + (20u << 20) + 524288);     // 4 MB
    __bf16* AO     = (__bf16*)(wsb + (24u << 20) + 524288);     // 4 MB -> ~28.5 MB

    hipLaunchKernelGGL(k_setup, dim3(6400), dim3(256), 0, stream,
                       x, Wqkv, Wproj, topo, Wfreq, xb, Wqkvb, Wprojb, cosb, sinb);
    hipLaunchKernelGGL(k_qkv_mfma, dim3(512), dim3(256), 0, stream,
                       xb, Wqkvb, cosb, sinb, Qb, Kb, Vtb);
    hipLaunchKernelGGL(k_attn8, dim3(LSEQ / 64, H_N, BATCH), dim3(256), 0, stream,
                       Qb, Kb, Vtb, AO);
    hipLaunchKernelGGL(k_proj_mfma, dim3(512), dim3(256), 0, stream,
                       AO, Wprojb, out);
}